// Round 3
// baseline (1113.023 us; speedup 1.0000x reference)
//
#include <hip/hip_runtime.h>

#define TSTEPS 1023
#define GAMMA  (0.01f / 32.0f)   // LR * d(mean sq)/dy factor: 2/(64*2) folded
#define EPSV   1e-5f

// workspace layout (float offsets)
#define WS_HS 0       // 64*64 hs table
#define WS_G  4096    // 64*64 gram
#define WS_Z0 8192    // 64*16 initial Ztilde = hs@w1 + b1

typedef float v2f __attribute__((ext_vector_type(2)));

__device__ __forceinline__ float rdlane(float v, int lane) {
    return __int_as_float(__builtin_amdgcn_readlane(__float_as_int(v), lane));
}
template<int CTRL>
__device__ __forceinline__ float dppmov(float x) {
    // quad_perm / row_ror move; all rows+banks enabled
    return __int_as_float(__builtin_amdgcn_update_dpp(0, __float_as_int(x), CTRL, 0xF, 0xF, true));
}
template<int PAT>
__device__ __forceinline__ float swzx(float x) {
    return __int_as_float(__builtin_amdgcn_ds_swizzle(__float_as_int(x), PAT));
}
__device__ __forceinline__ float bperm(int addr, float x) {
    return __int_as_float(__builtin_amdgcn_ds_bpermute(addr, __float_as_int(x)));
}
__host__ __device__ constexpr int lane_for_j(int j) {
    // J(l) = 8*b0 + 4*b1 + 2*b4 + b5  ->  lane with bits (b0,b1,b4,b5) set from j
    return ((j >> 3) & 1) | (((j >> 2) & 1) << 1) | (((j >> 1) & 1) << 4) | ((j & 1) << 5);
}

// ---------------- kernel A: hs table (per-token embed->FFN->LN) ----------------
__global__ void hs_kernel(const float* __restrict__ embed,
                          const float* __restrict__ ffw1, const float* __restrict__ ffb1,
                          const float* __restrict__ ffw2, const float* __restrict__ ffb2,
                          const float* __restrict__ lng,  const float* __restrict__ lnb,
                          float* __restrict__ ws) {
    __shared__ float e[64];
    __shared__ float a1[128];
    int w = blockIdx.x;
    int tid = threadIdx.x;
    if (tid < 64) e[tid] = embed[w * 64 + tid];
    __syncthreads();
    float z1 = ffb1[tid];
    for (int x = 0; x < 64; ++x) z1 += e[x] * ffw1[x * 128 + tid];
    a1[tid] = fmaxf(z1, 0.0f);
    __syncthreads();
    if (tid < 64) {
        float f = ffb2[tid];
        for (int i = 0; i < 128; ++i) f += a1[i] * ffw2[i * 64 + tid];
        float hv = e[tid] + f;
        float s = hv;
#pragma unroll
        for (int m = 32; m >= 1; m >>= 1) s += __shfl_xor(s, m);
        float mu = s * (1.0f / 64.0f);
        float dv = hv - mu;
        float vs = dv * dv;
#pragma unroll
        for (int m = 32; m >= 1; m >>= 1) vs += __shfl_xor(vs, m);
        float rstd = 1.0f / sqrtf(vs * (1.0f / 64.0f) + EPSV);
        ws[WS_HS + w * 64 + tid] = dv * rstd * lng[tid] + lnb[tid];
    }
}

// ---------------- kernel B: Gram matrix + Ztilde0 ----------------
__global__ void gz_kernel(const float* __restrict__ w1, const float* __restrict__ b1,
                          float* __restrict__ ws) {
    __shared__ float row[64];
    int w = blockIdx.x, tid = threadIdx.x;
    row[tid] = ws[WS_HS + w * 64 + tid];
    __syncthreads();
    float g = 0.0f;
    for (int x = 0; x < 64; ++x) g += row[x] * ws[WS_HS + tid * 64 + x];
    ws[WS_G + w * 64 + tid] = g;
    if (tid < 16) {
        float z = b1[tid];
        for (int x = 0; x < 64; ++x) z += row[x] * w1[x * 16 + tid];
        ws[WS_Z0 + w * 16 + tid] = z;
    }
}

// ---------------- main kernel: 2 batches per wave, interleaved chains ----------------
// one wave (64 lanes) per block, each wave runs TWO independent TTT scans.
// lane h owns W2[:,h], b2_h, Ztilde row h (regs + LDS mirror) for each chain.
// Reduction: DPP quad_perm folds (xor1,xor2) -> row_ror:4/8 orbit sums ->
// ds_swizzle xor16 fold -> ds_bpermute xor32 fold. Only 3 DS ops on chain.
__launch_bounds__(64, 1)
__global__ void ttt_kernel(const int* __restrict__ seq,
                           const float* __restrict__ w2g, const float* __restrict__ b2i,
                           const float* __restrict__ outw, const float* __restrict__ outb,
                           const float* __restrict__ ws, float* __restrict__ out) {
    __shared__ float hs[4096];
    __shared__ float G[4096];
    __shared__ int   sq[2][2048];
    __shared__ __align__(16) float Z[2][64 * 20];   // row stride 20: conflict-free b128
    __shared__ float ctxbuf[2][64];

    const int lane = threadIdx.x;
    const int bA = blockIdx.x * 2, bB = bA + 1;

    // ---- staging (single wave: DS in-order, no barriers needed) ----
    {
        float4* hv = (float4*)hs; const float4* sv = (const float4*)(ws + WS_HS);
#pragma unroll
        for (int m = 0; m < 16; ++m) hv[m * 64 + lane] = sv[m * 64 + lane];
        float4* gv = (float4*)G; const float4* gs = (const float4*)(ws + WS_G);
#pragma unroll
        for (int m = 0; m < 16; ++m) gv[m * 64 + lane] = gs[m * 64 + lane];
        int4* q0 = (int4*)sq[0]; const int4* s0 = (const int4*)(seq + bA * 2048);
#pragma unroll
        for (int m = 0; m < 8; ++m) q0[m * 64 + lane] = s0[m * 64 + lane];
        int4* q1 = (int4*)sq[1]; const int4* s1 = (const int4*)(seq + bB * 2048);
#pragma unroll
        for (int m = 0; m < 8; ++m) q1[m * 64 + lane] = s1[m * 64 + lane];
    }

    v2f W2p[2][8], Zrp[2][8], zz[2][8];
    float b2v[2], vv[2];
    int   tk[2];

#pragma unroll
    for (int i = 0; i < 8; ++i) {
        v2f w;
        w.x = w2g[(2 * i) * 64 + lane];
        w.y = w2g[(2 * i + 1) * 64 + lane];
        W2p[0][i] = w; W2p[1][i] = w;
    }
    b2v[0] = b2v[1] = b2i[lane];
    {
        const float4* z0 = (const float4*)(ws + WS_Z0 + lane * 16);
        float4 u0 = z0[0], u1 = z0[1], u2 = z0[2], u3 = z0[3];
        Zrp[0][0] = {u0.x, u0.y}; Zrp[0][1] = {u0.z, u0.w};
        Zrp[0][2] = {u1.x, u1.y}; Zrp[0][3] = {u1.z, u1.w};
        Zrp[0][4] = {u2.x, u2.y}; Zrp[0][5] = {u2.z, u2.w};
        Zrp[0][6] = {u3.x, u3.y}; Zrp[0][7] = {u3.z, u3.w};
#pragma unroll
        for (int i = 0; i < 8; ++i) Zrp[1][i] = Zrp[0][i];
        float4* za = (float4*)(Z[0] + lane * 20);
        za[0] = u0; za[1] = u1; za[2] = u2; za[3] = u3;
        float4* zb = (float4*)(Z[1] + lane * 20);
        zb[0] = u0; zb[1] = u1; zb[2] = u2; zb[3] = u3;
    }

    // init z, vv per chain
#pragma unroll
    for (int c = 0; c < 2; ++c) {
        tk[c] = sq[c][0];
        const float4* zr = (const float4*)(Z[c] + tk[c] * 20);
        float4 u0 = zr[0], u1 = zr[1], u2 = zr[2], u3 = zr[3];
        zz[c][0] = {u0.x, u0.y}; zz[c][1] = {u0.z, u0.w};
        zz[c][2] = {u1.x, u1.y}; zz[c][3] = {u1.z, u1.w};
        zz[c][4] = {u2.x, u2.y}; zz[c][5] = {u2.z, u2.w};
        zz[c][6] = {u3.x, u3.y}; zz[c][7] = {u3.z, u3.w};
        vv[c] = hs[sq[c][1] * 64 + lane];
    }

    const bool bl0 = (lane & 1) != 0;
    const bool bl1 = (lane & 2) != 0;
    const bool bl4 = (lane & 16) != 0;
    const bool bl5 = (lane & 32) != 0;
    const int  xaddr = (lane ^ 32) << 2;

    for (int t = 0; t < TSTEPS; ++t) {
        const bool last = (t == TSTEPS - 1);
        const int  base = last ? 2046 : (2 * t + 2);

        int   tkn[2];
        float4 e0[2], e1[2], e2[2], e3[2];
        float vnx[2], crr[2], czr[2];
#pragma unroll
        for (int c = 0; c < 2; ++c) {
            int2 pr = *(const int2*)(sq[c] + base);
            tkn[c] = last ? pr.y : pr.x;            // last iter: query token sq[2047]
            const int tvn = pr.y;
            const float4* zr = (const float4*)(Z[c] + tkn[c] * 20);  // Ztilde_t[tkn]
            e0[c] = zr[0]; e1[c] = zr[1]; e2[c] = zr[2]; e3[c] = zr[3];
            vnx[c] = hs[tvn * 64 + lane];
            crr[c] = G[tk[c] * 64 + lane];
            czr[c] = G[tk[c] * 64 + tkn[c]];
        }

        // ---- forward (packed) ----
        v2f  ap[2][8];
        float d[2];
#pragma unroll
        for (int c = 0; c < 2; ++c) {
            const v2f zero2 = {0.0f, 0.0f};
#pragma unroll
            for (int i = 0; i < 8; ++i) ap[c][i] = __builtin_elementwise_max(zz[c][i], zero2);
            v2f acc0 = ap[c][0] * W2p[c][0] + ap[c][1] * W2p[c][1];
            v2f acc1 = ap[c][2] * W2p[c][2] + ap[c][3] * W2p[c][3];
            v2f acc2 = ap[c][4] * W2p[c][4] + ap[c][5] * W2p[c][5];
            v2f acc3 = ap[c][6] * W2p[c][6] + ap[c][7] * W2p[c][7];
            v2f accv = (acc0 + acc1) + (acc2 + acc3);
            float y = b2v[c] + accv.x + accv.y;
            d[c] = y - vv[c];
        }

        // ---- p, W2/b2 update, cross-lane reduction ----
        float u[2];
#pragma unroll
        for (int c = 0; c < 2; ++c) {
            float ps[16];
#pragma unroll
            for (int i = 0; i < 8; ++i) {
                v2f pp = W2p[c][i] * d[c];          // pre-update W2
                ps[2 * i] = pp.x; ps[2 * i + 1] = pp.y;
            }
            const float sd = GAMMA * d[c];
            b2v[c] -= sd;
#pragma unroll
            for (int i = 0; i < 8; ++i) W2p[c][i] = W2p[c][i] - sd * ap[c][i];

            // S1: fold (j, j+8) over xor1 (quad_perm)
            float q[8];
#pragma unroll
            for (int j = 0; j < 8; ++j) {
                float keep = bl0 ? ps[j + 8] : ps[j];
                float give = bl0 ? ps[j] : ps[j + 8];
                q[j] = keep + dppmov<0xB1>(give);   // quad_perm [1,0,3,2]
            }
            // S2: fold (j, j+4) over xor2
            float r[4];
#pragma unroll
            for (int j = 0; j < 4; ++j) {
                float keep = bl1 ? q[j + 4] : q[j];
                float give = bl1 ? q[j] : q[j + 4];
                r[j] = keep + dppmov<0x4E>(give);   // quad_perm [2,3,0,1]
            }
            // S3/S4: within-row stride-4 orbit sums (ror4, ror8)
#pragma unroll
            for (int j = 0; j < 4; ++j) {
                r[j] = r[j] + dppmov<0x124>(r[j]);  // row_ror:4
                r[j] = r[j] + dppmov<0x128>(r[j]);  // row_ror:8
            }
            // S5: fold (j, j+2) over xor16 (ds_swizzle, within 32 lanes)
            float w0, w1;
            {
                float keep = bl4 ? r[2] : r[0];
                float give = bl4 ? r[0] : r[2];
                w0 = keep + swzx<0x401F>(give);
                float keep1 = bl4 ? r[3] : r[1];
                float give1 = bl4 ? r[1] : r[3];
                w1 = keep1 + swzx<0x401F>(give1);
            }
            // S6: fold (0,1) over xor32 (ds_bpermute, wave-wide)
            {
                float keep = bl5 ? w1 : w0;
                float give = bl5 ? w0 : w1;
                u[c] = keep + bperm(xaddr, give);
            }
        }
        // lane l now holds da[J(l)], J = 8*b0 + 4*b1 + 2*b4 + b5

        // ---- apply: dz, Ztilde row update, next-z correction, writeback ----
#pragma unroll
        for (int c = 0; c < 2; ++c) {
            const float cr = GAMMA * crr[c] + GAMMA;
            const float cz = GAMMA * czr[c] + GAMMA;
            float da[16];
#pragma unroll
            for (int j = 0; j < 16; ++j) da[j] = rdlane(u[c], lane_for_j(j));
            v2f dzp[8];
#pragma unroll
            for (int i = 0; i < 8; ++i) {
                float dz0 = (zz[c][i].x > 0.0f) ? da[2 * i] : 0.0f;
                float dz1 = (zz[c][i].y > 0.0f) ? da[2 * i + 1] : 0.0f;
                dzp[i] = {dz0, dz1};
            }
            v2f zq[8] = { {e0[c].x, e0[c].y}, {e0[c].z, e0[c].w},
                          {e1[c].x, e1[c].y}, {e1[c].z, e1[c].w},
                          {e2[c].x, e2[c].y}, {e2[c].z, e2[c].w},
                          {e3[c].x, e3[c].y}, {e3[c].z, e3[c].w} };
#pragma unroll
            for (int i = 0; i < 8; ++i) {
                Zrp[c][i] = Zrp[c][i] - cr * dzp[i];
                zz[c][i]  = zq[i]     - cz * dzp[i];
            }
            float4* zw = (float4*)(Z[c] + lane * 20);
            zw[0] = make_float4(Zrp[c][0].x, Zrp[c][0].y, Zrp[c][1].x, Zrp[c][1].y);
            zw[1] = make_float4(Zrp[c][2].x, Zrp[c][2].y, Zrp[c][3].x, Zrp[c][3].y);
            zw[2] = make_float4(Zrp[c][4].x, Zrp[c][4].y, Zrp[c][5].x, Zrp[c][5].y);
            zw[3] = make_float4(Zrp[c][6].x, Zrp[c][6].y, Zrp[c][7].x, Zrp[c][7].y);
            vv[c] = vnx[c];
            tk[c] = tkn[c];
        }
    }

    // ---- final eval + output projection for both chains ----
#pragma unroll
    for (int c = 0; c < 2; ++c) {
        const v2f zero2 = {0.0f, 0.0f};
        v2f acc = {0.0f, 0.0f};
#pragma unroll
        for (int i = 0; i < 8; ++i)
            acc = acc + __builtin_elementwise_max(zz[c][i], zero2) * W2p[c][i];
        ctxbuf[c][lane] = b2v[c] + acc.x + acc.y;
    }
    float o0 = outb[lane], o1 = o0;
    for (int h = 0; h < 64; ++h) {
        float wv_ = outw[h * 64 + lane];
        o0 += ctxbuf[0][h] * wv_;
        o1 += ctxbuf[1][h] * wv_;
    }
    out[bA * 64 + lane] = o0;
    out[bB * 64 + lane] = o1;
}

// ---------------- launcher ----------------
extern "C" void kernel_launch(void* const* d_in, const int* in_sizes, int n_in,
                              void* d_out, int out_size, void* d_ws, size_t ws_size,
                              hipStream_t stream) {
    const int*   seq   = (const int*)d_in[0];
    const float* embed = (const float*)d_in[1];
    const float* ffw1  = (const float*)d_in[2];
    const float* ffb1  = (const float*)d_in[3];
    const float* ffw2  = (const float*)d_in[4];
    const float* ffb2  = (const float*)d_in[5];
    const float* lng   = (const float*)d_in[6];
    const float* lnb   = (const float*)d_in[7];
    const float* w1    = (const float*)d_in[8];
    const float* b1    = (const float*)d_in[9];
    const float* w2    = (const float*)d_in[10];
    const float* b2    = (const float*)d_in[11];
    const float* outw  = (const float*)d_in[12];
    const float* outb  = (const float*)d_in[13];
    float* ws  = (float*)d_ws;
    float* out = (float*)d_out;

    hipLaunchKernelGGL(hs_kernel, dim3(64), dim3(128), 0, stream,
                       embed, ffw1, ffb1, ffw2, ffb2, lng, lnb, ws);
    hipLaunchKernelGGL(gz_kernel, dim3(64), dim3(64), 0, stream, w1, b1, ws);
    hipLaunchKernelGGL(ttt_kernel, dim3(128), dim3(64), 0, stream,
                       seq, w2, b2, outw, outb, ws, out);
}

// Round 4
// 648.325 us; speedup vs baseline: 1.7168x; 1.7168x over previous
//
#include <hip/hip_runtime.h>

#define TSTEPS 1023
#define GAMMA  (0.01f / 32.0f)   // LR * dL/dy scale: 2/(64*2) folded
#define EPSV   1e-5f

// workspace layout (float offsets)
#define WS_HS 0       // 64*64 hs table
#define WS_G  4096    // 64*64 gram
#define WS_Z0 8192    // 64*16 initial Ztilde = hs@w1 + b1

__device__ __forceinline__ float rdlane(float v, int lane) {
    return __int_as_float(__builtin_amdgcn_readlane(__float_as_int(v), lane));
}
template<int CTRL>
__device__ __forceinline__ float dppmov(float x) {
    // quad_perm / row_ror move; all rows+banks enabled, bound_ctrl=1
    return __int_as_float(__builtin_amdgcn_update_dpp(0, __float_as_int(x), CTRL, 0xF, 0xF, true));
}
template<int PAT>
__device__ __forceinline__ float swzx(float x) {
    return __int_as_float(__builtin_amdgcn_ds_swizzle(__float_as_int(x), PAT));
}
__device__ __forceinline__ float bperm(int addr, float x) {
    return __int_as_float(__builtin_amdgcn_ds_bpermute(addr, __float_as_int(x)));
}

// ---------------- kernel A: hs table (per-token embed->FFN->LN) ----------------
__global__ void hs_kernel(const float* __restrict__ embed,
                          const float* __restrict__ ffw1, const float* __restrict__ ffb1,
                          const float* __restrict__ ffw2, const float* __restrict__ ffb2,
                          const float* __restrict__ lng,  const float* __restrict__ lnb,
                          float* __restrict__ ws) {
    __shared__ float e[64];
    __shared__ float a1[128];
    int w = blockIdx.x;
    int tid = threadIdx.x;
    if (tid < 64) e[tid] = embed[w * 64 + tid];
    __syncthreads();
    float z1 = ffb1[tid];
    for (int x = 0; x < 64; ++x) z1 += e[x] * ffw1[x * 128 + tid];
    a1[tid] = fmaxf(z1, 0.0f);
    __syncthreads();
    if (tid < 64) {
        float f = ffb2[tid];
        for (int i = 0; i < 128; ++i) f += a1[i] * ffw2[i * 64 + tid];
        float hv = e[tid] + f;
        float s = hv;
#pragma unroll
        for (int m = 32; m >= 1; m >>= 1) s += __shfl_xor(s, m);
        float mu = s * (1.0f / 64.0f);
        float dv = hv - mu;
        float vs = dv * dv;
#pragma unroll
        for (int m = 32; m >= 1; m >>= 1) vs += __shfl_xor(vs, m);
        float rstd = 1.0f / sqrtf(vs * (1.0f / 64.0f) + EPSV);
        ws[WS_HS + w * 64 + tid] = dv * rstd * lng[tid] + lnb[tid];
    }
}

// ---------------- kernel B: Gram matrix + Ztilde0 ----------------
__global__ void gz_kernel(const float* __restrict__ w1, const float* __restrict__ b1,
                          float* __restrict__ ws) {
    __shared__ float row[64];
    int w = blockIdx.x, tid = threadIdx.x;
    row[tid] = ws[WS_HS + w * 64 + tid];
    __syncthreads();
    float g = 0.0f;
    for (int x = 0; x < 64; ++x) g += row[x] * ws[WS_HS + tid * 64 + x];
    ws[WS_G + w * 64 + tid] = g;
    if (tid < 16) {
        float z = b1[tid];
        for (int x = 0; x < 64; ++x) z += row[x] * w1[x * 16 + tid];
        ws[WS_Z0 + w * 16 + tid] = z;
    }
}

// ---------------- main kernel: per-batch sequential TTT scan ----------------
// one wave (64 lanes) per batch. lane h owns W2[:,h], b2_h, and Ztilde row h
// (regs, mirrored to LDS for the broadcast read). No barriers in the loop.
// Reduction: quad_perm folds (xor1,xor2) -> row_ror:4/8 orbit sums (VALU) ->
// ONE parallel DS orbit stage (swz-xor16 + bperm^32 + bperm^48) -> readlane.
__launch_bounds__(64, 1)
__global__ void ttt_kernel(const int* __restrict__ seq,
                           const float* __restrict__ w2, const float* __restrict__ b2i,
                           const float* __restrict__ outw, const float* __restrict__ outb,
                           const float* __restrict__ ws, float* __restrict__ out) {
    __shared__ float hs[64 * 64];
    __shared__ float G[64 * 64];
    __shared__ int   sq[2048];
    __shared__ __align__(16) float Z[64 * 20];   // row stride 20: conflict-free b128
    __shared__ float ctxbuf[64];

    const int b    = blockIdx.x;
    const int lane = threadIdx.x;

    {   // vectorized staging
        float4*       hv = (float4*)hs;
        const float4* sv = (const float4*)(ws + WS_HS);
#pragma unroll
        for (int m = 0; m < 16; ++m) hv[m * 64 + lane] = sv[m * 64 + lane];
        float4*       gv = (float4*)G;
        const float4* gs = (const float4*)(ws + WS_G);
#pragma unroll
        for (int m = 0; m < 16; ++m) gv[m * 64 + lane] = gs[m * 64 + lane];
        int4*       qv = (int4*)sq;
        const int4* qs = (const int4*)(seq + b * 2048);
#pragma unroll
        for (int m = 0; m < 8; ++m) qv[m * 64 + lane] = qs[m * 64 + lane];
    }

    float W2c[16], Zr[16];
#pragma unroll
    for (int j = 0; j < 16; ++j) W2c[j] = w2[j * 64 + lane];
    float b2v = b2i[lane];
    {
        const float4* z0 = (const float4*)(ws + WS_Z0 + lane * 16);
        float4 u0 = z0[0], u1 = z0[1], u2 = z0[2], u3 = z0[3];
        Zr[0] = u0.x;  Zr[1] = u0.y;  Zr[2] = u0.z;  Zr[3] = u0.w;
        Zr[4] = u1.x;  Zr[5] = u1.y;  Zr[6] = u1.z;  Zr[7] = u1.w;
        Zr[8] = u2.x;  Zr[9] = u2.y;  Zr[10] = u2.z; Zr[11] = u2.w;
        Zr[12] = u3.x; Zr[13] = u3.y; Zr[14] = u3.z; Zr[15] = u3.w;
        float4* zr = (float4*)(Z + lane * 20);
        zr[0] = u0; zr[1] = u1; zr[2] = u2; zr[3] = u3;
    }
    __syncthreads();

    int tk = sq[0];
    float z[16];
    {
        const float4* zp = (const float4*)(Z + tk * 20);
        float4 u0 = zp[0], u1 = zp[1], u2 = zp[2], u3 = zp[3];
        z[0] = u0.x;  z[1] = u0.y;  z[2] = u0.z;  z[3] = u0.w;
        z[4] = u1.x;  z[5] = u1.y;  z[6] = u1.z;  z[7] = u1.w;
        z[8] = u2.x;  z[9] = u2.y;  z[10] = u2.z; z[11] = u2.w;
        z[12] = u3.x; z[13] = u3.y; z[14] = u3.z; z[15] = u3.w;
    }
    float vv = hs[sq[1] * 64 + lane];

    const bool bl0 = (lane & 1) != 0;
    const bool bl1 = (lane & 2) != 0;
    const int  xaddr32 = (lane ^ 32) << 2;
    const int  xaddr48 = (lane ^ 48) << 2;

    for (int t = 0; t < TSTEPS; ++t) {
        const bool last = (t == TSTEPS - 1);
        const int  base = last ? 2046 : (2 * t + 2);
        const int2 pr   = *(const int2*)(sq + base);
        const int  tkn  = last ? pr.y : pr.x;   // last iter: final query token sq[2047]
        const int  tvn  = pr.y;

        // ---- early off-chain loads (consumed late) ----
        const float4* zp = (const float4*)(Z + tkn * 20);   // reads Ztilde_t[tkn] (pre-update)
        const float4 e0 = zp[0], e1 = zp[1], e2 = zp[2], e3 = zp[3];
        const float vnext = hs[tvn * 64 + lane];
        const float cr = GAMMA * G[tk * 64 + lane] + GAMMA;  // gamma*(G[lane][tk]+1)
        const float cz = GAMMA * G[tk * 64 + tkn] + GAMMA;   // gamma*(G[tkn][tk]+1)

        // ---- forward ----
        float a[16], mk[16];
#pragma unroll
        for (int j = 0; j < 16; ++j) {
            a[j]  = fmaxf(z[j], 0.0f);
            mk[j] = (z[j] > 0.0f) ? 1.0f : 0.0f;
        }
        float y0 = 0.f, y1 = 0.f, y2 = 0.f, y3 = 0.f;
#pragma unroll
        for (int j = 0; j < 16; j += 4) {
            y0 += a[j] * W2c[j];
            y1 += a[j + 1] * W2c[j + 1];
            y2 += a[j + 2] * W2c[j + 2];
            y3 += a[j + 3] * W2c[j + 3];
        }
        const float y = b2v + ((y0 + y1) + (y2 + y3));
        const float d = y - vv;

        // ---- p (pre-update W2), then local W2/b2 update ----
        float p[16];
#pragma unroll
        for (int j = 0; j < 16; ++j) p[j] = W2c[j] * d;
        const float sd = GAMMA * d;
        b2v -= sd;
#pragma unroll
        for (int j = 0; j < 16; ++j) W2c[j] -= sd * a[j];

        // ---- reduction ----
        // S1: fold (j, j+8) over xor1 (quad_perm) -> 8 values, index bit b0
        float q[8];
#pragma unroll
        for (int j = 0; j < 8; ++j) {
            float keep = bl0 ? p[j + 8] : p[j];
            float give = bl0 ? p[j] : p[j + 8];
            q[j] = keep + dppmov<0xB1>(give);   // quad_perm [1,0,3,2]
        }
        // S2: fold (j, j+4) over xor2 -> 4 values, index bit b1
        float r[4];
#pragma unroll
        for (int j = 0; j < 4; ++j) {
            float keep = bl1 ? q[j + 4] : q[j];
            float give = bl1 ? q[j] : q[j + 4];
            r[j] = keep + dppmov<0x4E>(give);   // quad_perm [2,3,0,1]
        }
        // S3: within-row stride-4 orbit sums (VALU DPP, direction-agnostic)
#pragma unroll
        for (int j = 0; j < 4; ++j) {
            r[j] = r[j] + dppmov<0x124>(r[j]);  // row_ror:4
            r[j] = r[j] + dppmov<0x128>(r[j]);  // row_ror:8
        }
        // S4: cross-row orbit {l, l^16, l^32, l^48} — ONE parallel DS stage
        float tot[4];
#pragma unroll
        for (int j = 0; j < 4; ++j) {
            float s16 = swzx<0x401F>(r[j]);         // xor16 within 32-half
            float s32 = bperm(xaddr32, r[j]);
            float s48 = bperm(xaddr48, r[j]);
            tot[j] = (r[j] + s16) + (s32 + s48);
        }
        // da[m] lives in tot[m&3] at lane ((m>>3) + 2*((m>>2)&1)); m = j + 4*b1 + 8*b0

        // ---- apply: dz, Ztilde row update (regs), next-z correction ----
        const float zq[16] = {e0.x, e0.y, e0.z, e0.w, e1.x, e1.y, e1.z, e1.w,
                              e2.x, e2.y, e2.z, e2.w, e3.x, e3.y, e3.z, e3.w};
#pragma unroll
        for (int m = 0; m < 16; ++m) {
            const float da = rdlane(tot[m & 3], ((m >> 3) & 1) + 2 * ((m >> 2) & 1));
            const float dz = mk[m] * da;
            Zr[m] -= cr * dz;
            z[m] = zq[m] - cz * dz;
        }
        // commit this lane's Ztilde row to LDS (off-chain; DS pipe in-order)
        float4* zw = (float4*)(Z + lane * 20);
        zw[0] = make_float4(Zr[0], Zr[1], Zr[2], Zr[3]);
        zw[1] = make_float4(Zr[4], Zr[5], Zr[6], Zr[7]);
        zw[2] = make_float4(Zr[8], Zr[9], Zr[10], Zr[11]);
        zw[3] = make_float4(Zr[12], Zr[13], Zr[14], Zr[15]);

        vv = vnext;
        tk = tkn;
    }

    // ---- final eval: z = Ztilde_final[q_token]; ctx = relu(z)@W2_f + b2_f ----
    float ctx = b2v;
#pragma unroll
    for (int j = 0; j < 16; ++j) ctx += fmaxf(z[j], 0.0f) * W2c[j];
    ctxbuf[lane] = ctx;
    __syncthreads();

    float o = outb[lane];
    for (int hh = 0; hh < 64; ++hh) o += ctxbuf[hh] * outw[hh * 64 + lane];
    out[b * 64 + lane] = o;
}

// ---------------- launcher ----------------
extern "C" void kernel_launch(void* const* d_in, const int* in_sizes, int n_in,
                              void* d_out, int out_size, void* d_ws, size_t ws_size,
                              hipStream_t stream) {
    const int*   seq   = (const int*)d_in[0];
    const float* embed = (const float*)d_in[1];
    const float* ffw1  = (const float*)d_in[2];
    const float* ffb1  = (const float*)d_in[3];
    const float* ffw2  = (const float*)d_in[4];
    const float* ffb2  = (const float*)d_in[5];
    const float* lng   = (const float*)d_in[6];
    const float* lnb   = (const float*)d_in[7];
    const float* w1    = (const float*)d_in[8];
    const float* b1    = (const float*)d_in[9];
    const float* w2    = (const float*)d_in[10];
    const float* b2    = (const float*)d_in[11];
    const float* outw  = (const float*)d_in[12];
    const float* outb  = (const float*)d_in[13];
    float* ws  = (float*)d_ws;
    float* out = (float*)d_out;

    hipLaunchKernelGGL(hs_kernel, dim3(64), dim3(128), 0, stream,
                       embed, ffw1, ffb1, ffw2, ffb2, lng, lnb, ws);
    hipLaunchKernelGGL(gz_kernel, dim3(64), dim3(64), 0, stream, w1, b1, ws);
    hipLaunchKernelGGL(ttt_kernel, dim3(256), dim3(64), 0, stream,
                       seq, w2, b2, outw, outb, ws, out);
}